// Round 1
// baseline (362.576 us; speedup 1.0000x reference)
//
#include <hip/hip_runtime.h>
#include <hip/hip_bf16.h>

typedef __bf16 bf16_t;
typedef __bf16 bf16x4 __attribute__((ext_vector_type(4)));
typedef __bf16 bf16x8 __attribute__((ext_vector_type(8)));
typedef float f32x4 __attribute__((ext_vector_type(4)));

#define BATCH 128
#define NS 512
#define DIM 256
#define BT 128   // output tile (M = N = 128)
#define BK 32    // K step
#define LDSK 40  // padded LDS k-stride in bf16 elements (80 B rows, 16B-aligned)

// ---------------- Kernel 0: fp32 row norms ||d_i||^2 ----------------
__global__ __launch_bounds__(256) void norms_kernel(const float* __restrict__ dv,
                                                    float* __restrict__ n2) {
    const int row  = blockIdx.x * 4 + (threadIdx.x >> 6);  // one wave per row
    const int lane = threadIdx.x & 63;
    const float4 v = *reinterpret_cast<const float4*>(dv + (size_t)row * DIM + lane * 4);
    float s = v.x * v.x + v.y * v.y + v.z * v.z + v.w * v.w;
#pragma unroll
    for (int off = 32; off >= 1; off >>= 1) s += __shfl_down(s, off, 64);
    if (lane == 0) n2[row] = s;
}

// ------- Kernel 1: batched Gram tile + fused epilogue -> per-block partial -------
// grid: (16, BATCH); block: 256 threads = 4 waves (2x2), each wave owns 64x64.
__global__ __launch_bounds__(256) void gram_kernel(const float* __restrict__ dv,
                                                   const float* __restrict__ Smat,
                                                   const float* __restrict__ n2,
                                                   float* __restrict__ partial) {
    const int tile = blockIdx.x;          // 0..15
    const int b    = blockIdx.y;
    const int ti   = tile >> 2, tj = tile & 3;
    const int t    = threadIdx.x;
    const int wave = t >> 6, lane = t & 63;
    const int wr   = wave >> 1, wc = wave & 1;

    __shared__ bf16_t sA[BT * LDSK];
    __shared__ bf16_t sB[BT * LDSK];
    __shared__ float red[4];

    const float* Abase = dv + ((size_t)b * NS + (size_t)ti * BT) * DIM;
    const float* Bbase = dv + ((size_t)b * NS + (size_t)tj * BT) * DIM;

    f32x4 acc[4][4];
#pragma unroll
    for (int m = 0; m < 4; ++m)
#pragma unroll
        for (int n = 0; n < 4; ++n) acc[m][n] = (f32x4)(0.0f);

    const int fr = lane & 15;      // fragment row/col within 16
    const int g  = lane >> 4;      // k-group 0..3 (8 consecutive k each)

    for (int ks = 0; ks < DIM; ks += BK) {
        // stage: 128 rows x 32 k fp32 per tile; each thread 4 float4 per tile
        float4 ra[4], rb[4];
#pragma unroll
        for (int i = 0; i < 4; ++i) {
            const int c   = i * 256 + t;
            const int row = c >> 3;
            const int kc  = (c & 7) * 4;
            ra[i] = *reinterpret_cast<const float4*>(Abase + (size_t)row * DIM + ks + kc);
            rb[i] = *reinterpret_cast<const float4*>(Bbase + (size_t)row * DIM + ks + kc);
        }
        __syncthreads();  // previous compute done reading LDS
#pragma unroll
        for (int i = 0; i < 4; ++i) {
            const int c   = i * 256 + t;
            const int row = c >> 3;
            const int kc  = (c & 7) * 4;
            bf16x4 va = { (bf16_t)ra[i].x, (bf16_t)ra[i].y, (bf16_t)ra[i].z, (bf16_t)ra[i].w };
            bf16x4 vb = { (bf16_t)rb[i].x, (bf16_t)rb[i].y, (bf16_t)rb[i].z, (bf16_t)rb[i].w };
            *reinterpret_cast<bf16x4*>(&sA[row * LDSK + kc]) = va;
            *reinterpret_cast<bf16x4*>(&sB[row * LDSK + kc]) = vb;
        }
        __syncthreads();  // writes visible

        bf16x8 afrag[4], bfrag[4];
#pragma unroll
        for (int m = 0; m < 4; ++m)
            afrag[m] = *reinterpret_cast<const bf16x8*>(&sA[(wr * 64 + m * 16 + fr) * LDSK + g * 8]);
#pragma unroll
        for (int n = 0; n < 4; ++n)
            bfrag[n] = *reinterpret_cast<const bf16x8*>(&sB[(wc * 64 + n * 16 + fr) * LDSK + g * 8]);
#pragma unroll
        for (int m = 0; m < 4; ++m)
#pragma unroll
            for (int n = 0; n < 4; ++n)
                acc[m][n] = __builtin_amdgcn_mfma_f32_16x16x32_bf16(afrag[m], bfrag[n], acc[m][n], 0, 0, 0);
    }

    // epilogue: C/D layout col = lane&15, row = (lane>>4)*4 + j  [guide-verified]
    float local = 0.0f;
    const float* n2b = n2 + (size_t)b * NS;
    const int rowbase = ti * BT + wr * 64;
    const int colbase = tj * BT + wc * 64;
#pragma unroll
    for (int m = 0; m < 4; ++m) {
#pragma unroll
        for (int n = 0; n < 4; ++n) {
            const int gi0 = rowbase + m * 16 + g * 4;
            const int gj  = colbase + n * 16 + fr;
            const float ncol = n2b[gj];
#pragma unroll
            for (int j = 0; j < 4; ++j) {
                const int gi = gi0 + j;
                const float cij = acc[m][n][j];
                float sq = n2b[gi] + ncol - 2.0f * cij;
                sq = fmaxf(sq, 0.0f);
                const float dist = sqrtf(sq);
                const float kd = __expf(-dist);
                const float s = Smat[(size_t)gi * NS + gj];
                const float w = (s > 0.0f) ? 1.0f : 0.0f;
                float d = (gi == gj) ? (1.0f - s) : (kd - s);
                d *= w;
                local += d * d;
            }
        }
    }
#pragma unroll
    for (int off = 32; off >= 1; off >>= 1) local += __shfl_down(local, off, 64);
    if (lane == 0) red[wave] = local;
    __syncthreads();
    if (t == 0) partial[(size_t)b * 16 + tile] = red[0] + red[1] + red[2] + red[3];
}

// ---------------- Kernel 2: finalize (denom + per-batch sqrt + sum) ----------------
__global__ __launch_bounds__(256) void finalize_kernel(const float* __restrict__ Smat,
                                                       const float* __restrict__ partial,
                                                       float* __restrict__ out) {
    const int t = threadIdx.x;
    const int lane = t & 63, wave = t >> 6;
    __shared__ float sred[4];
    __shared__ float sred2[4];

    // denom^2 = || W - I ||_F^2
    float dacc = 0.0f;
    for (int idx = t; idx < NS * NS; idx += 256) {
        const float s = Smat[idx];
        const int i = idx >> 9, j = idx & (NS - 1);
        const float w = (s > 0.0f) ? 1.0f : 0.0f;
        const float e = (i == j) ? 1.0f : 0.0f;
        const float d = w - e;
        dacc += d * d;
    }
#pragma unroll
    for (int off = 32; off >= 1; off >>= 1) dacc += __shfl_down(dacc, off, 64);
    if (lane == 0) sred[wave] = dacc;
    __syncthreads();
    const float denom = sqrtf(sred[0] + sred[1] + sred[2] + sred[3]);

    float lsum = 0.0f;
    if (t < BATCH) {
        float ss = 0.0f;
#pragma unroll
        for (int k = 0; k < 16; ++k) ss += partial[(size_t)t * 16 + k];
        lsum = 2.0f * sqrtf(ss) / denom;
    }
#pragma unroll
    for (int off = 32; off >= 1; off >>= 1) lsum += __shfl_down(lsum, off, 64);
    if (lane == 0) sred2[wave] = lsum;
    __syncthreads();
    if (t == 0) out[0] = sred2[0] + sred2[1] + sred2[2] + sred2[3];
}

extern "C" void kernel_launch(void* const* d_in, const int* in_sizes, int n_in,
                              void* d_out, int out_size, void* d_ws, size_t ws_size,
                              hipStream_t stream) {
    const float* dv   = (const float*)d_in[0];   // [128,512,256] fp32
    const float* Smat = (const float*)d_in[1];   // [512,512] fp32
    float* out = (float*)d_out;

    float* n2      = (float*)d_ws;               // BATCH*NS floats
    float* partial = n2 + (size_t)BATCH * NS;    // BATCH*16 floats

    norms_kernel<<<dim3(BATCH * NS / 4), 256, 0, stream>>>(dv, n2);
    gram_kernel<<<dim3(16, BATCH), 256, 0, stream>>>(dv, Smat, n2, partial);
    finalize_kernel<<<dim3(1), 256, 0, stream>>>(Smat, partial, out);
}

// Round 2
// 88.921 us; speedup vs baseline: 4.0775x; 4.0775x over previous
//
#include <hip/hip_runtime.h>
#include <hip/hip_bf16.h>

typedef __bf16 bf16_t;
typedef __bf16 bf16x4 __attribute__((ext_vector_type(4)));
typedef __bf16 bf16x8 __attribute__((ext_vector_type(8)));
typedef float f32x4 __attribute__((ext_vector_type(4)));

#define BATCH 128
#define NS 512
#define DIM 256
#define BT 128   // output tile (M = N = 128)
#define BK 32    // K step
#define LDSK 40  // padded LDS k-stride in bf16 elements (80 B rows, 16B-aligned)
#define DENOM_BLOCKS 128

// ---------------- Kernel 0: fp32 row norms ||d_i||^2 ----------------
__global__ __launch_bounds__(256) void norms_kernel(const float* __restrict__ dv,
                                                    float* __restrict__ n2) {
    const int row  = blockIdx.x * 4 + (threadIdx.x >> 6);  // one wave per row
    const int lane = threadIdx.x & 63;
    const float4 v = *reinterpret_cast<const float4*>(dv + (size_t)row * DIM + lane * 4);
    float s = v.x * v.x + v.y * v.y + v.z * v.z + v.w * v.w;
#pragma unroll
    for (int off = 32; off >= 1; off >>= 1) s += __shfl_down(s, off, 64);
    if (lane == 0) n2[row] = s;
}

// ---------------- Kernel 0b: denom^2 partials = ||W - I||_F^2 ----------------
// grid: DENOM_BLOCKS x 256 threads; float4 loads; per-block partial (exact ints).
__global__ __launch_bounds__(256) void denom_kernel(const float* __restrict__ Smat,
                                                    float* __restrict__ dpartial) {
    const int t = threadIdx.x;
    const int lane = t & 63, wave = t >> 6;
    __shared__ float sred[4];
    // 512*512/4 = 65536 float4; per block: 65536/DENOM_BLOCKS = 512; per thread: 2
    float acc = 0.0f;
    const int base = blockIdx.x * 512;  // in float4 units
#pragma unroll
    for (int r = 0; r < 2; ++r) {
        const int v4 = base + r * 256 + t;          // float4 index
        const float4 s4 = reinterpret_cast<const float4*>(Smat)[v4];
        const int idx0 = v4 * 4;
        const int i = idx0 >> 9;
#pragma unroll
        for (int c = 0; c < 4; ++c) {
            const float s = (&s4.x)[c];
            const int j = (idx0 + c) & (NS - 1);
            const float w = (s > 0.0f) ? 1.0f : 0.0f;
            const float e = (i == j) ? 1.0f : 0.0f;
            const float d = w - e;
            acc += d * d;
        }
    }
#pragma unroll
    for (int off = 32; off >= 1; off >>= 1) acc += __shfl_down(acc, off, 64);
    if (lane == 0) sred[wave] = acc;
    __syncthreads();
    if (t == 0) dpartial[blockIdx.x] = sred[0] + sred[1] + sred[2] + sred[3];
}

// ------- Kernel 1: batched Gram tile + fused epilogue -> per-block partial -------
// grid: (16, BATCH); block: 256 threads = 4 waves (2x2), each wave owns 64x64.
__global__ __launch_bounds__(256) void gram_kernel(const float* __restrict__ dv,
                                                   const float* __restrict__ Smat,
                                                   const float* __restrict__ n2,
                                                   float* __restrict__ partial) {
    const int tile = blockIdx.x;          // 0..15
    const int b    = blockIdx.y;
    const int ti   = tile >> 2, tj = tile & 3;
    const int t    = threadIdx.x;
    const int wave = t >> 6, lane = t & 63;
    const int wr   = wave >> 1, wc = wave & 1;

    __shared__ bf16_t sA[BT * LDSK];
    __shared__ bf16_t sB[BT * LDSK];
    __shared__ float red[4];

    const float* Abase = dv + ((size_t)b * NS + (size_t)ti * BT) * DIM;
    const float* Bbase = dv + ((size_t)b * NS + (size_t)tj * BT) * DIM;

    f32x4 acc[4][4];
#pragma unroll
    for (int m = 0; m < 4; ++m)
#pragma unroll
        for (int n = 0; n < 4; ++n) acc[m][n] = (f32x4)(0.0f);

    const int fr = lane & 15;      // fragment row/col within 16
    const int g  = lane >> 4;      // k-group 0..3 (8 consecutive k each)

    for (int ks = 0; ks < DIM; ks += BK) {
        // stage: 128 rows x 32 k fp32 per tile; each thread 4 float4 per tile
        float4 ra[4], rb[4];
#pragma unroll
        for (int i = 0; i < 4; ++i) {
            const int c   = i * 256 + t;
            const int row = c >> 3;
            const int kc  = (c & 7) * 4;
            ra[i] = *reinterpret_cast<const float4*>(Abase + (size_t)row * DIM + ks + kc);
            rb[i] = *reinterpret_cast<const float4*>(Bbase + (size_t)row * DIM + ks + kc);
        }
        __syncthreads();  // previous compute done reading LDS
#pragma unroll
        for (int i = 0; i < 4; ++i) {
            const int c   = i * 256 + t;
            const int row = c >> 3;
            const int kc  = (c & 7) * 4;
            bf16x4 va = { (bf16_t)ra[i].x, (bf16_t)ra[i].y, (bf16_t)ra[i].z, (bf16_t)ra[i].w };
            bf16x4 vb = { (bf16_t)rb[i].x, (bf16_t)rb[i].y, (bf16_t)rb[i].z, (bf16_t)rb[i].w };
            *reinterpret_cast<bf16x4*>(&sA[row * LDSK + kc]) = va;
            *reinterpret_cast<bf16x4*>(&sB[row * LDSK + kc]) = vb;
        }
        __syncthreads();  // writes visible

        bf16x8 afrag[4], bfrag[4];
#pragma unroll
        for (int m = 0; m < 4; ++m)
            afrag[m] = *reinterpret_cast<const bf16x8*>(&sA[(wr * 64 + m * 16 + fr) * LDSK + g * 8]);
#pragma unroll
        for (int n = 0; n < 4; ++n)
            bfrag[n] = *reinterpret_cast<const bf16x8*>(&sB[(wc * 64 + n * 16 + fr) * LDSK + g * 8]);
#pragma unroll
        for (int m = 0; m < 4; ++m)
#pragma unroll
            for (int n = 0; n < 4; ++n)
                acc[m][n] = __builtin_amdgcn_mfma_f32_16x16x32_bf16(afrag[m], bfrag[n], acc[m][n], 0, 0, 0);
    }

    // epilogue: C/D layout col = lane&15, row = (lane>>4)*4 + j  [guide-verified]
    float local = 0.0f;
    const float* n2b = n2 + (size_t)b * NS;
    const int rowbase = ti * BT + wr * 64;
    const int colbase = tj * BT + wc * 64;
#pragma unroll
    for (int m = 0; m < 4; ++m) {
#pragma unroll
        for (int n = 0; n < 4; ++n) {
            const int gi0 = rowbase + m * 16 + g * 4;
            const int gj  = colbase + n * 16 + fr;
            const float ncol = n2b[gj];
#pragma unroll
            for (int j = 0; j < 4; ++j) {
                const int gi = gi0 + j;
                const float cij = acc[m][n][j];
                float sq = n2b[gi] + ncol - 2.0f * cij;
                sq = fmaxf(sq, 0.0f);
                const float dist = sqrtf(sq);
                const float kd = __expf(-dist);
                const float s = Smat[(size_t)gi * NS + gj];
                const float w = (s > 0.0f) ? 1.0f : 0.0f;
                float d = (gi == gj) ? (1.0f - s) : (kd - s);
                d *= w;
                local += d * d;
            }
        }
    }
#pragma unroll
    for (int off = 32; off >= 1; off >>= 1) local += __shfl_down(local, off, 64);
    if (lane == 0) red[wave] = local;
    __syncthreads();
    if (t == 0) partial[(size_t)b * 16 + tile] = red[0] + red[1] + red[2] + red[3];
}

// ---------------- Kernel 2: finalize (sum denom partials + per-batch sqrt + sum) ----------------
__global__ __launch_bounds__(256) void finalize_kernel(const float* __restrict__ dpartial,
                                                       const float* __restrict__ partial,
                                                       float* __restrict__ out) {
    const int t = threadIdx.x;
    const int lane = t & 63, wave = t >> 6;
    __shared__ float sred[4];
    __shared__ float sred2[4];

    float dacc = (t < DENOM_BLOCKS) ? dpartial[t] : 0.0f;
#pragma unroll
    for (int off = 32; off >= 1; off >>= 1) dacc += __shfl_down(dacc, off, 64);
    if (lane == 0) sred[wave] = dacc;
    __syncthreads();
    const float denom = sqrtf(sred[0] + sred[1] + sred[2] + sred[3]);

    float lsum = 0.0f;
    if (t < BATCH) {
        float ss = 0.0f;
#pragma unroll
        for (int k = 0; k < 16; ++k) ss += partial[(size_t)t * 16 + k];
        lsum = 2.0f * sqrtf(ss) / denom;
    }
#pragma unroll
    for (int off = 32; off >= 1; off >>= 1) lsum += __shfl_down(lsum, off, 64);
    if (lane == 0) sred2[wave] = lsum;
    __syncthreads();
    if (t == 0) out[0] = sred2[0] + sred2[1] + sred2[2] + sred2[3];
}

extern "C" void kernel_launch(void* const* d_in, const int* in_sizes, int n_in,
                              void* d_out, int out_size, void* d_ws, size_t ws_size,
                              hipStream_t stream) {
    const float* dv   = (const float*)d_in[0];   // [128,512,256] fp32
    const float* Smat = (const float*)d_in[1];   // [512,512] fp32
    float* out = (float*)d_out;

    float* n2       = (float*)d_ws;                    // BATCH*NS floats
    float* partial  = n2 + (size_t)BATCH * NS;         // BATCH*16 floats
    float* dpartial = partial + (size_t)BATCH * 16;    // DENOM_BLOCKS floats

    norms_kernel<<<dim3(BATCH * NS / 4), 256, 0, stream>>>(dv, n2);
    denom_kernel<<<dim3(DENOM_BLOCKS), 256, 0, stream>>>(Smat, dpartial);
    gram_kernel<<<dim3(16, BATCH), 256, 0, stream>>>(dv, Smat, n2, partial);
    finalize_kernel<<<dim3(1), 256, 0, stream>>>(dpartial, partial, out);
}